// Round 9
// baseline (634.378 us; speedup 1.0000x reference)
//
#include <hip/hip_runtime.h>
#include <math.h>

#define CDIM 32
#define HWDIM 2304            // 48*48
#define BDIM 16
#define PPW 8                 // pixels per wave (8 lanes per pixel)
#define NTHREADS 256          // 4 waves => 32 pixels per block
#define PPB 32
#define CROWS 256             // rc-rows per chunk (32 KB) - R3 staging
#define ZOFF (BDIM * CDIM * HWDIM)   // z elements, then 16 logdet floats

// R8 lesson: (256,3) -> ~128 regs/thread -> A spills (WRITE 107MB, 238us).
// Occupancy is pinned at 2 waves/SIMD by A's 128 floats. R3/R5/R7 all sit
// at 114-130us regardless of memory strategy; the invariant is the ~4K-inst
// unrolled body with ~1100 cross-lane ops (2 DPP + cndmask per (j,k) link).
// R9: right-looking LU + LDS-row publication. At step k the pivot row is
// FINAL: the owner writes its remaining row slice once to a 36-word
// per-pixel LDS buffer; all 8 lanes read it back as b128s (same-address
// broadcast = free fan-out, 8 pixels hit 32 distinct banks at stride 36).
// Solver inst count drops ~45%, each bv feeds 4 fmas. L stored in place
// (strict-lower m), U non-unit-diagonal with per-row reciprocals rr[4] for
// back-sub. DPP bcast8 (R7-proven) kept only for y-elim/back-sub (63 links).
// Staging = R3's proven row-chunk ring, verbatim.
__device__ __forceinline__ void gload_lds16(const float* g, float* l) {
    __builtin_amdgcn_global_load_lds(
        (const __attribute__((address_space(1))) float*)g,
        (__attribute__((address_space(3))) float*)l, 16, 0, 0);
}

// Broadcast lane (group_base + k7) to all 8 lanes of each aligned 8-lane
// group (R7-proven DPP pair). k7 compile-time.
__device__ __forceinline__ float bcast8(float x, int k7) {
    int v = __float_as_int(x), b;
    switch (k7) {
    case 0: b = __builtin_amdgcn_update_dpp(v, v, 0x00, 0xF, 0xF, false);
            b = __builtin_amdgcn_update_dpp(b, b, 0x114, 0xF, 0xA, false); break;
    case 1: b = __builtin_amdgcn_update_dpp(v, v, 0x55, 0xF, 0xF, false);
            b = __builtin_amdgcn_update_dpp(b, b, 0x114, 0xF, 0xA, false); break;
    case 2: b = __builtin_amdgcn_update_dpp(v, v, 0xAA, 0xF, 0xF, false);
            b = __builtin_amdgcn_update_dpp(b, b, 0x114, 0xF, 0xA, false); break;
    case 3: b = __builtin_amdgcn_update_dpp(v, v, 0xFF, 0xF, 0xF, false);
            b = __builtin_amdgcn_update_dpp(b, b, 0x114, 0xF, 0xA, false); break;
    case 4: b = __builtin_amdgcn_update_dpp(v, v, 0x00, 0xF, 0xF, false);
            b = __builtin_amdgcn_update_dpp(b, b, 0x104, 0xF, 0x5, false); break;
    case 5: b = __builtin_amdgcn_update_dpp(v, v, 0x55, 0xF, 0xF, false);
            b = __builtin_amdgcn_update_dpp(b, b, 0x104, 0xF, 0x5, false); break;
    case 6: b = __builtin_amdgcn_update_dpp(v, v, 0xAA, 0xF, 0xF, false);
            b = __builtin_amdgcn_update_dpp(b, b, 0x104, 0xF, 0x5, false); break;
    default: b = __builtin_amdgcn_update_dpp(v, v, 0xFF, 0xF, 0xF, false);
            b = __builtin_amdgcn_update_dpp(b, b, 0x104, 0xF, 0x5, false); break;
    }
    return __int_as_float(b);
}

__global__ __launch_bounds__(NTHREADS, 2)
void solve_kernel(const float* __restrict__ input,
                  const float* __restrict__ weight,
                  const float* __restrict__ logdet,
                  float* __restrict__ out) {
    const int t    = threadIdx.x;
    const int lane = t & 63;
    const int wv   = t >> 6;           // wave 0..3
    const int h    = lane & 7;         // row class: owns rows i = 8q + h
    const int p    = lane >> 3;        // pixel-in-wave 0..7

    const int blk  = blockIdx.x;
    const int b    = blk / (HWDIM / PPB);       // 72 blocks per batch image
    const int pb   = (blk % (HWDIM / PPB)) * PPB;  // block pixel base
    const int pixl = wv * PPW + p;              // pixel-in-block 0..31
    const int pix0 = pb + wv * PPW;             // wave pixel base (logdet cond)
    const int pix  = pb + pixl;

    __shared__ float lds[2][CROWS * CDIM];          // 2 x 32KB chunk ring
    __shared__ __align__(16) float ubuf[PPB][36];   // per-pixel U-row buffer

    // ---- x: scalar loads, issued first (oldest in vmcnt order) ----
    const float* xp = input + (size_t)b * CDIM * HWDIM + (size_t)h * HWDIM + pix;
    float y[4];
    #pragma unroll
    for (int r = 0; r < 4; ++r) y[r] = xp[(size_t)(r * 8) * HWDIM];
    asm volatile("" ::: "memory");     // pin: x loads oldest in vmcnt order

    // ---- DMA staging (R3-verbatim): chunk r = matrix rows [8r, 8r+8) ----
    // rcl = wv*64 + q*8 + sg; LDS dest linear (word rcl*32 + sp*4); global
    // source slot pre-swizzled by g = rcl>>5 (wave-uniform per q -> full
    // 128B lines). Read: A[r][j] at word (h*32+j)*32 + ((ps^h)<<2)+pc.
    const int sg = lane >> 3;
    const int sp = lane & 7;
    const int ps = pixl >> 2, pc = pixl & 3;
    const float* wbase = weight + (size_t)b * (CDIM * CDIM) * HWDIM + pb;
    const float* srcA = wbase + (size_t)(wv * 64 + sg) * HWDIM
                              + ((sp ^ (2 * wv)) << 2);
    const float* srcB = wbase + (size_t)(wv * 64 + sg) * HWDIM
                              + ((sp ^ (2 * wv + 1)) << 2);

    auto stage = [&](int r, int buf) {
        float* lbase = &lds[buf][(wv * 64) * CDIM];
        #pragma unroll
        for (int q = 0; q < 8; ++q) {
            const float* s = (q < 4 ? srcA : srcB)
                           + (size_t)(r * 256 + q * 8) * HWDIM;
            gload_lds16(s, lbase + q * 8 * CDIM);
        }
    };

    stage(0, 0);
    asm volatile("" ::: "memory");
    stage(1, 1);

    float A[4][CDIM];
    #pragma unroll
    for (int r = 0; r < 4; ++r) {
        if (r < 3) asm volatile("s_waitcnt vmcnt(8)" ::: "memory");
        else       asm volatile("s_waitcnt vmcnt(0)" ::: "memory");
        __builtin_amdgcn_s_barrier();
        asm volatile("" ::: "memory");
        #pragma unroll
        for (int j = 0; j < CDIM; ++j)
            A[r][j] = lds[r & 1][(h * CDIM + j) * CDIM + ((ps ^ h) << 2) + pc];
        if (r < 2) {
            asm volatile("s_waitcnt lgkmcnt(0)" ::: "memory");
            __builtin_amdgcn_s_barrier();
            asm volatile("" ::: "memory");
            stage(r + 2, r & 1);
        }
    }

    // ---- right-looking LU with LDS pivot-row publication ----
    float* ub = ubuf[pixl];
    float rr[4] = {0.0f, 0.0f, 0.0f, 0.0f};
    float lacc = 0.0f;

    #pragma unroll
    for (int k = 0; k < CDIM; ++k) {
        const int tr = k >> 3, k7 = k & 7, q0 = k >> 2;
        // owner publishes its (final) row slice [k..31]
        if (h == k7) {
            #pragma unroll
            for (int j = k; j < CDIM; ++j) ub[j] = A[tr][j];
        }
        asm volatile("s_waitcnt lgkmcnt(0)" ::: "memory");
        // all lanes read the row back: b128, same-address broadcast within
        // a pixel; 8 pixels at stride 36 words -> 32 distinct banks.
        float4 bv4[8];
        #pragma unroll
        for (int qq = 0; qq < 8; ++qq)
            if (qq >= q0)
                bv4[qq] = *reinterpret_cast<const float4*>(&ub[qq * 4]);

        const float piv  = reinterpret_cast<const float*>(&bv4[q0])[k & 3];
        const float rcpv = __builtin_amdgcn_rcpf(piv);
        lacc += __log2f(fabsf(piv));
        rr[tr] = (h == k7) ? rcpv : rr[tr];

        float m[4];
        #pragma unroll
        for (int q = 0; q < 4; ++q) {
            if (q < tr)       m[q] = 0.0f;
            else if (q == tr) m[q] = (h > k7) ? A[tr][k] * rcpv : 0.0f;
            else              m[q] = A[q][k] * rcpv;
        }
        // store L in place (strict lower); U rows/pivot untouched
        A[tr][k] = (h > k7) ? m[tr] : A[tr][k];
        #pragma unroll
        for (int q = tr + 1; q < 4; ++q) A[q][k] = m[q];

        #pragma unroll
        for (int j = k + 1; j < CDIM; ++j) {
            const float bvj = reinterpret_cast<const float*>(&bv4[j >> 2])[j & 3];
            #pragma unroll
            for (int q = tr; q < 4; ++q)
                A[q][j] = fmaf(-m[q], bvj, A[q][j]);
        }
    }

    // ---- forward-eliminate y with stored L (unit diag -> STRICT mask) ----
    #pragma unroll
    for (int k = 0; k < CDIM; ++k) {
        const int tr = k >> 3, k7 = k & 7;
        float bq = bcast8(y[tr], k7);
        float mk = (h > k7) ? A[tr][k] : 0.0f;
        y[tr] = fmaf(-mk, bq, y[tr]);
        #pragma unroll
        for (int q = tr + 1; q < 4; ++q) y[q] = fmaf(-A[q][k], bq, y[q]);
    }

    // ---- back-substitution (non-unit U: owner scales by rr, then bcast) --
    #pragma unroll
    for (int k = CDIM - 1; k >= 0; --k) {
        const int tr = k >> 3, k7 = k & 7;
        y[tr] = (h == k7) ? y[tr] * rr[tr] : y[tr];   // z_k finalized
        if (k > 0) {
            float bz = bcast8(y[tr], k7);
            float cm = (h < k7) ? A[tr][k] : 0.0f;    // U entries above pivot
            y[tr] = fmaf(-cm, bz, y[tr]);
            #pragma unroll
            for (int q = 0; q < tr; ++q)
                y[q] = fmaf(-A[q][k], bz, y[q]);
        }
    }
    // y[r] = z[8r + h]

    // ---- store z (dense 32B-segment pattern) ----
    float* zp = out + (size_t)b * CDIM * HWDIM + (size_t)h * HWDIM + pix;
    #pragma unroll
    for (int r = 0; r < 4; ++r) zp[(size_t)(r * 8) * HWDIM] = y[r];

    // ---- logdet: lacc identical across a pixel's 8 lanes (piv came from a
    // shared LDS read); 3 xor-shuffles sum the wave's 8 pixel-groups. ----
    float v2 = lacc;
    v2 += __shfl_xor(v2, 8);
    v2 += __shfl_xor(v2, 16);
    v2 += __shfl_xor(v2, 32);
    if (lane == 0) {
        float add = -v2 * 0.69314718055994531f;  // ln2 * sum(log2|piv|)
        if (pix0 == 0) add += logdet[b];         // exactly one wave per b
        atomicAdd(&out[ZOFF + b], add);
    }
}

extern "C" void kernel_launch(void* const* d_in, const int* in_sizes, int n_in,
                              void* d_out, int out_size, void* d_ws, size_t ws_size,
                              hipStream_t stream) {
    const float* input  = (const float*)d_in[0];
    const float* weight = (const float*)d_in[1];
    const float* logdet = (const float*)d_in[2];
    float* out = (float*)d_out;

    solve_kernel<<<BDIM * (HWDIM / PPB), NTHREADS, 0, stream>>>(input, weight,
                                                                logdet, out);
}

// Round 10
// 323.279 us; speedup vs baseline: 1.9623x; 1.9623x over previous
//
#include <hip/hip_runtime.h>
#include <math.h>

#define CDIM 32
#define HWDIM 2304            // 48*48
#define BDIM 16
#define NTHREADS 512          // 8 waves x 4 pixels/wave = 32 pixels per block
#define PPB 32
#define ZOFF (BDIM * CDIM * HWDIM)   // z elements, then 16 logdet floats

// R9 lesson (3rd spill): 8 lanes/pixel => A[4][32]=128 floats/thread pins
// the kernel at 2 waves/SIMD with zero headroom; every added live value
// spills, and VALUBusy 25% shows 75% dependency-stall with nobody to fill.
// R10: 16 lanes/pixel. Each lane owns rows i=16r+h16 (r=0,1): A[2][32]=64
// floats -> ~95 regs -> 4 waves/SIMD (launch_bounds(512,4); 2 blocks/CU x
// 64KB LDS = 128 <= 160). Same per-wave instruction count as R7 (half rows
// x same link count), twice the waves to cover the stalls.
// Broadcast = bcast16: 3 DPP movs within the aligned 16-lane DPP row
// (quad_perm -> dist-4 -> dist-8; masks traced per source quadrant).
// Solver = R7's HW-proven left-looking algebra (owner stores 1-rcp; L in
// place), mapped h->h16, k7->k15, 2 row slots. Staging = R3's ring with
// G = rcl>>5 source swizzle (exactly wave-uniform here); read banks:
// slot=W8^(h16&7) x pc=g -> 32 distinct, conflict-free.
__device__ __forceinline__ void gload_lds16(const float* g, float* l) {
    __builtin_amdgcn_global_load_lds(
        (const __attribute__((address_space(1))) float*)g,
        (__attribute__((address_space(3))) float*)l, 16, 0, 0);
}

// Broadcast lane (16*group + k15) to all 16 lanes of its aligned group.
// k15 compile-time (call sites fully unrolled; switches fold).
// Step1 quad_perm([s,s,s,s]): every quad holds its own lane s.
// Step2/3 move source quad qk across the 16-lane row:
//  qk=0: shr4 mask 0x2 (b1<-b0), shr8 mask 0xC (b2,b3<-b0,b1)
//  qk=1: shl4 mask 0x1 (b0<-b1), shr8 mask 0xC
//  qk=2: shr4 mask 0x8 (b3<-b2), shl8 mask 0x3 (b0,b1<-b2,b3)
//  qk=3: shl4 mask 0x4 (b2<-b3), shl8 mask 0x3
__device__ __forceinline__ float bcast16(float x, int k15) {
    int v = __float_as_int(x), b;
    switch (k15 & 3) {
    case 0:  b = __builtin_amdgcn_update_dpp(v, v, 0x00, 0xF, 0xF, false); break;
    case 1:  b = __builtin_amdgcn_update_dpp(v, v, 0x55, 0xF, 0xF, false); break;
    case 2:  b = __builtin_amdgcn_update_dpp(v, v, 0xAA, 0xF, 0xF, false); break;
    default: b = __builtin_amdgcn_update_dpp(v, v, 0xFF, 0xF, 0xF, false); break;
    }
    switch (k15 >> 2) {
    case 0:
        b = __builtin_amdgcn_update_dpp(b, b, 0x114, 0xF, 0x2, false);
        b = __builtin_amdgcn_update_dpp(b, b, 0x118, 0xF, 0xC, false); break;
    case 1:
        b = __builtin_amdgcn_update_dpp(b, b, 0x104, 0xF, 0x1, false);
        b = __builtin_amdgcn_update_dpp(b, b, 0x118, 0xF, 0xC, false); break;
    case 2:
        b = __builtin_amdgcn_update_dpp(b, b, 0x114, 0xF, 0x8, false);
        b = __builtin_amdgcn_update_dpp(b, b, 0x108, 0xF, 0x3, false); break;
    default:
        b = __builtin_amdgcn_update_dpp(b, b, 0x104, 0xF, 0x4, false);
        b = __builtin_amdgcn_update_dpp(b, b, 0x108, 0xF, 0x3, false); break;
    }
    return __int_as_float(b);
}

__global__ __launch_bounds__(NTHREADS, 4)
void solve_kernel(const float* __restrict__ input,
                  const float* __restrict__ weight,
                  const float* __restrict__ logdet,
                  float* __restrict__ out) {
    const int t    = threadIdx.x;
    const int lane = t & 63;
    const int W8   = t >> 6;           // wave 0..7
    const int h16  = lane & 15;        // row class: owns rows i = 16r + h16
    const int g    = lane >> 4;        // pixel-in-wave 0..3

    const int blk  = blockIdx.x;
    const int b    = blk / (HWDIM / PPB);       // 72 blocks per batch image
    const int pb   = (blk % (HWDIM / PPB)) * PPB;  // block pixel base
    const int pixl = W8 * 4 + g;                // pixel-in-block 0..31
    const int pix0 = pb + W8 * 4;               // wave pixel base (logdet cond)
    const int pix  = pb + pixl;

    __shared__ float lds[2][256 * CDIM];        // 2 x 32KB chunk ring

    // ---- x: 2 scalar loads, issued first (oldest in vmcnt order) ----
    const float* xp = input + (size_t)b * CDIM * HWDIM + (size_t)h16 * HWDIM + pix;
    float y[2];
    #pragma unroll
    for (int r = 0; r < 2; ++r) y[r] = xp[(size_t)(r * 16) * HWDIM];
    asm volatile("" ::: "memory");     // pin: x loads oldest in vmcnt order

    // ---- DMA staging: chunk c = rc-rows [256c, 256c+256) x 32 pixels ----
    // Wave W8 stages rcl = W8*32 + q*8 + sg (q=0..3); lane 16B slot sp.
    // LDS linear dest word rcl*32 + sp*4; global source slot pre-swizzled
    // by G = rcl>>5 = W8 (wave-uniform -> full 128B lines, permuted).
    const int sg = lane >> 3;
    const int sp = lane & 7;
    const float* wbase = weight + (size_t)b * (CDIM * CDIM) * HWDIM + pb;
    const float* src = wbase + (size_t)(W8 * 32 + sg) * HWDIM + ((sp ^ W8) << 2);

    auto stage = [&](int c, int buf) {
        float* lbase = &lds[buf][(W8 * 32) * CDIM];
        #pragma unroll
        for (int q = 0; q < 4; ++q)
            gload_lds16(src + (size_t)(c * 256 + q * 8) * HWDIM,
                        lbase + q * 8 * CDIM);
    };

    stage(0, 0);
    asm volatile("" ::: "memory");
    stage(1, 1);

    // ---- gather A: chunk c holds rows i in [8c,8c+8) ----
    // Lane reads A[c>>1][j] iff (h16>>3)==(c&1), from word
    // ((h16&7)*32 + j)*32 + ((W8 ^ (h16&7))<<2) + g  (32 distinct banks).
    float A[2][CDIM];
    #pragma unroll
    for (int c = 0; c < 4; ++c) {
        if (c < 3) asm volatile("s_waitcnt vmcnt(4)" ::: "memory");
        else       asm volatile("s_waitcnt vmcnt(0)" ::: "memory");
        __builtin_amdgcn_s_barrier();
        asm volatile("" ::: "memory");
        if ((h16 >> 3) == (c & 1)) {
            const int rbase = (h16 & 7) * 32;
            const int slot  = ((W8 ^ (h16 & 7)) << 2) + g;
            #pragma unroll
            for (int j = 0; j < CDIM; ++j)
                A[c >> 1][j] = lds[c & 1][(rbase + j) * 32 + slot];
        }
        if (c < 2) {
            asm volatile("s_waitcnt lgkmcnt(0)" ::: "memory");
            __builtin_amdgcn_s_barrier();
            asm volatile("" ::: "memory");
            stage(c + 2, c & 1);
        }
    }

    // ---- left-looking LU (R7 algebra, 2 row slots) ----
    // Owner of pivot k stores (1 - rcp); L stored in place below.
    float lacc = 0.0f;
    #pragma unroll
    for (int j = 0; j < CDIM; ++j) {
        #pragma unroll
        for (int k = 0; k < j; ++k) {
            const int trk = k >> 4, k15 = k & 15;
            float bv = bcast16(A[trk][j], k15);
            float mk = (h16 >= k15) ? A[trk][k] : 0.0f;
            A[trk][j] = fmaf(-mk, bv, A[trk][j]);
            if (trk == 0) A[1][j] = fmaf(-A[1][k], bv, A[1][j]);
        }
        const int trj = j >> 4, j15 = j & 15;
        float bp = bcast16(A[trj][j], j15);
        float rcpv = __builtin_amdgcn_rcpf(bp);
        lacc += __log2f(fabsf(bp));
        A[trj][j] = (h16 > j15) ? A[trj][j] * rcpv
                                : ((h16 == j15) ? (1.0f - rcpv) : A[trj][j]);
        if (trj == 0) A[1][j] *= rcpv;
    }

    // ---- forward-eliminate y with stored L ----
    #pragma unroll
    for (int k = 0; k < CDIM; ++k) {
        const int tr = k >> 4, k15 = k & 15;
        float bq = bcast16(y[tr], k15);
        float mk = (h16 >= k15) ? A[tr][k] : 0.0f;
        y[tr] = fmaf(-mk, bq, y[tr]);
        if (tr == 0) y[1] = fmaf(-A[1][k], bq, y[1]);
    }

    // ---- back-substitution (unit-diagonal U after owner scaling) ----
    #pragma unroll
    for (int k = CDIM - 1; k >= 1; --k) {
        const int tr = k >> 4, k15 = k & 15;
        float bz = bcast16(y[tr], k15);    // z[k] (rows finalize high->low)
        float cm = (h16 < k15) ? A[tr][k] : 0.0f;  // owner & done rows: no-op
        y[tr] = fmaf(-cm, bz, y[tr]);
        if (tr == 1) y[0] = fmaf(-A[0][k], bz, y[0]);
    }
    // y[r] = z[16r + h16]

    // ---- store z ----
    float* zp = out + (size_t)b * CDIM * HWDIM + (size_t)h16 * HWDIM + pix;
    #pragma unroll
    for (int r = 0; r < 2; ++r) zp[(size_t)(r * 16) * HWDIM] = y[r];

    // ---- logdet: lacc identical across a pixel's 16 lanes; 2 xor-shuffles
    // sum the wave's 4 pixel groups; one atomic per wave. ----
    float v2 = lacc;
    v2 += __shfl_xor(v2, 16);
    v2 += __shfl_xor(v2, 32);
    if (lane == 0) {
        float add = -v2 * 0.69314718055994531f;  // ln2 * sum(log2|piv|)
        if (pix0 == 0) add += logdet[b];         // exactly one wave per b
        atomicAdd(&out[ZOFF + b], add);
    }
}

extern "C" void kernel_launch(void* const* d_in, const int* in_sizes, int n_in,
                              void* d_out, int out_size, void* d_ws, size_t ws_size,
                              hipStream_t stream) {
    const float* input  = (const float*)d_in[0];
    const float* weight = (const float*)d_in[1];
    const float* logdet = (const float*)d_in[2];
    float* out = (float*)d_out;

    solve_kernel<<<BDIM * (HWDIM / PPB), NTHREADS, 0, stream>>>(input, weight,
                                                                logdet, out);
}